// Round 1
// baseline (3388.811 us; speedup 1.0000x reference)
//
#include <hip/hip_runtime.h>

// ---------------------------------------------------------------------------
// GRU stack: 3 layers (H=256,128,64) over [B=128,T=512,F=128] + dense sigmoid.
// Design: input projections hoisted into parallel MFMA GEMMs (gate-tuple
// layout); recurrences run on 8 persistent blocks (16 batch rows each, one
// 16x16 MFMA M-tile), 4 waves/block (1 wave/SIMD -> VGPR-resident U weights).
// fp32 master h-state in registers; bf16 only for MFMA operands.
// ---------------------------------------------------------------------------

typedef __attribute__((ext_vector_type(8))) __bf16 bf16x8;
typedef __attribute__((ext_vector_type(4))) float f32x4;

#define DEVINL __device__ __forceinline__

DEVINL unsigned short f2bf(float f) {  // RNE f32 -> bf16 bits
  unsigned int x = __float_as_uint(f);
  return (unsigned short)((x + 0x7fffu + ((x >> 16) & 1u)) >> 16);
}
DEVINL float bflo(unsigned int u) { return __uint_as_float(u << 16); }
DEVINL float bfhi(unsigned int u) { return __uint_as_float(u & 0xffff0000u); }

DEVINL float sigm(float x) {
#if __has_builtin(__builtin_amdgcn_rcpf)
  return __builtin_amdgcn_rcpf(1.0f + __expf(-x));
#else
  return 1.0f / (1.0f + __expf(-x));
#endif
}

DEVINL f32x4 mfma16(bf16x8 a, bf16x8 b, f32x4 c) {
  return __builtin_amdgcn_mfma_f32_16x16x32_bf16(a, b, c, 0, 0, 0);
}
DEVINL bf16x8 ldfrag(const unsigned short* p) {
  return *reinterpret_cast<const bf16x8*>(p);
}

// ---------------------------------------------------------------------------
// Weight permute: src fp32 [K,N] -> dst bf16 fragments.
// Fragment (ntile,ktile): 64 lanes x 8 bf16, lane l elem j = src[ktile*32 +
// (l>>4)*8 + j][ntile*16 + (l&15)]  (MFMA 16x16x32 B-operand layout).
// dst index = ((ntile*KT + ktile)*64 + l)*8 + j.
// ---------------------------------------------------------------------------
__global__ void kperm(const float* __restrict__ src, unsigned short* __restrict__ dst,
                      int K, int N) {
  int KT = K >> 5;
  int tile = blockIdx.x;
  int ntile = tile / KT, ktile = tile - ntile * KT;
  int l = threadIdx.x;
  int col = ntile * 16 + (l & 15);
  int krow = ktile * 32 + ((l >> 4) << 3);
  unsigned short tmp[8];
#pragma unroll
  for (int j = 0; j < 8; ++j) tmp[j] = f2bf(src[(size_t)(krow + j) * N + col]);
  uint4 v;
  v.x = (unsigned int)tmp[0] | ((unsigned int)tmp[1] << 16);
  v.y = (unsigned int)tmp[2] | ((unsigned int)tmp[3] << 16);
  v.z = (unsigned int)tmp[4] | ((unsigned int)tmp[5] << 16);
  v.w = (unsigned int)tmp[6] | ((unsigned int)tmp[7] << 16);
  *reinterpret_cast<uint4*>(dst + (size_t)(tile * 64 + l) * 8) = v;
}

// ---------------------------------------------------------------------------
// xg1 = text @ W1 + b1[0], written in gate-tuple layout:
// ushort idx = ((((bblk*512 + t)*16 + tau)*64 + lane)*12 + g*4 + j)
// where the scan's lane holds batch rows b = bblk*16 + (lane>>4)*4 + j,
// hidden col n = tau*16 + (lane&15), gate g in {z,r,h}.
// Block = (bblk, tchunk of 16 t). M-tile = 16 batch rows at fixed t, so the
// GEMM D-fragment lane mapping == scan tuple lane mapping (lane'==lane).
// ---------------------------------------------------------------------------
__global__ void __launch_bounds__(256) kxg1(const float* __restrict__ text,
                                            const unsigned short* __restrict__ W1p,
                                            const float* __restrict__ b1,
                                            unsigned short* __restrict__ xg1) {
  __shared__ __attribute__((aligned(16))) unsigned short alds[16 * 2184];  // [b][tt][136pad]
  const int bblk = blockIdx.x, tch = blockIdx.y;
  const int tid = threadIdx.x;
  // ---- stage text tile [16 b][16 t][128 f] -> LDS bf16 (padded) ----
  {
    int tt = tid >> 4, kc = tid & 15;
#pragma unroll
    for (int b = 0; b < 16; ++b) {
      const float* p = text + ((size_t)((bblk * 16 + b) * 512 + tch * 16 + tt)) * 128 + kc * 8;
      float4 f0 = *reinterpret_cast<const float4*>(p);
      float4 f1 = *reinterpret_cast<const float4*>(p + 4);
      uint4 v;
      v.x = (unsigned int)f2bf(f0.x) | ((unsigned int)f2bf(f0.y) << 16);
      v.y = (unsigned int)f2bf(f0.z) | ((unsigned int)f2bf(f0.w) << 16);
      v.z = (unsigned int)f2bf(f1.x) | ((unsigned int)f2bf(f1.y) << 16);
      v.w = (unsigned int)f2bf(f1.z) | ((unsigned int)f2bf(f1.w) << 16);
      *reinterpret_cast<uint4*>(&alds[b * 2184 + tt * 136 + kc * 8]) = v;
    }
  }
  __syncthreads();
  const int w = tid >> 6, l = tid & 63, lr = l >> 4, lc = l & 15;
  for (int mtg = 0; mtg < 4; ++mtg) {
    bf16x8 a[4][4];
#pragma unroll
    for (int m4 = 0; m4 < 4; ++m4)
#pragma unroll
      for (int kt = 0; kt < 4; ++kt)
        a[m4][kt] = ldfrag(&alds[lc * 2184 + (mtg * 4 + m4) * 136 + kt * 32 + lr * 8]);
    for (int ni = 0; ni < 12; ++ni) {
      int nt = w * 12 + ni;  // global n-tile 0..47
      bf16x8 bb[4];
#pragma unroll
      for (int kt = 0; kt < 4; ++kt)
        bb[kt] = ldfrag(W1p + (size_t)(nt * 4 + kt) * 512 + l * 8);
      float bias = b1[nt * 16 + lc];
      int g = nt >> 4, tau = nt & 15;
#pragma unroll
      for (int m4 = 0; m4 < 4; ++m4) {
        f32x4 acc = {0.f, 0.f, 0.f, 0.f};
#pragma unroll
        for (int kt = 0; kt < 4; ++kt) acc = mfma16(a[m4][kt], bb[kt], acc);
        int tglob = tch * 16 + mtg * 4 + m4;
        unsigned int u0 = (unsigned int)f2bf(acc[0] + bias) | ((unsigned int)f2bf(acc[1] + bias) << 16);
        unsigned int u1 = (unsigned int)f2bf(acc[2] + bias) | ((unsigned int)f2bf(acc[3] + bias) << 16);
        uint2 st; st.x = u0; st.y = u1;
        size_t base = ((((size_t)bblk * 512 + tglob) * 16 + tau) * 64 + l) * 12 + g * 4;
        *reinterpret_cast<uint2*>(xg1 + base) = st;
      }
    }
  }
}

// ---------------------------------------------------------------------------
// Layer-1 recurrence. 8 blocks x 256 threads (4 waves, 1/SIMD).
// Wave w owns hidden-col triples tau = {3w,3w+1,3w+2} (U-frags VGPR-resident)
// plus tau = 12+w (streamed from L2 each step; compiler may hoist).
// ---------------------------------------------------------------------------
__global__ void __launch_bounds__(256) kscan1(const unsigned short* __restrict__ xg1,
                                              const unsigned short* __restrict__ U1p,
                                              const float* __restrict__ b1,
                                              unsigned short* __restrict__ seq1) {
  __shared__ __attribute__((aligned(16))) unsigned short h1b[16 * 264];  // [16 rows][256+8 pad]
  const int bblk = blockIdx.x;
  const int tid = threadIdx.x;
  const int w = tid >> 6, l = tid & 63, lr = l >> 4, lc = l & 15;

  for (int i = tid; i < 16 * 264; i += 256) h1b[i] = 0;

  bf16x8 Bv[3][3][8];
#pragma unroll
  for (int ti = 0; ti < 3; ++ti)
#pragma unroll
    for (int g = 0; g < 3; ++g)
#pragma unroll
      for (int kt = 0; kt < 8; ++kt)
        Bv[ti][g][kt] = ldfrag(U1p + (size_t)((g * 16 + (w * 3 + ti)) * 8 + kt) * 512 + l * 8);

  float bz[4], br[4], bh[4];
#pragma unroll
  for (int ti = 0; ti < 4; ++ti) {
    int tau = (ti < 3) ? (w * 3 + ti) : (12 + w);
    int n = tau * 16 + lc;
    bz[ti] = b1[768 + n];
    br[ti] = b1[768 + 256 + n];
    bh[ti] = b1[768 + 512 + n];
  }

  const f32x4 zero4 = {0.f, 0.f, 0.f, 0.f};
  f32x4 h1f[4] = {zero4, zero4, zero4, zero4};

  __syncthreads();

  for (int t = 0; t < 512; ++t) {
    uint2 xzv[4], xrv[4], xhv[4];
#pragma unroll
    for (int ti = 0; ti < 4; ++ti) {
      int tau = (ti < 3) ? (w * 3 + ti) : (12 + w);
      const unsigned short* p = xg1 + ((((size_t)bblk * 512 + t) * 16 + tau) * 64 + l) * 12;
      xzv[ti] = *reinterpret_cast<const uint2*>(p);
      xrv[ti] = *reinterpret_cast<const uint2*>(p + 4);
      xhv[ti] = *reinterpret_cast<const uint2*>(p + 8);
    }
    bf16x8 Bs[3][8];
#pragma unroll
    for (int g = 0; g < 3; ++g)
#pragma unroll
      for (int kt = 0; kt < 8; ++kt)
        Bs[g][kt] = ldfrag(U1p + (size_t)((g * 16 + 12 + w) * 8 + kt) * 512 + l * 8);
    bf16x8 a[8];
#pragma unroll
    for (int kt = 0; kt < 8; ++kt)
      a[kt] = ldfrag(&h1b[lc * 264 + kt * 32 + lr * 8]);

#pragma unroll
    for (int ti = 0; ti < 4; ++ti) {
      f32x4 az = zero4, ar = zero4, ah = zero4;
#pragma unroll
      for (int kt = 0; kt < 8; ++kt) {
        az = mfma16(a[kt], (ti < 3) ? Bv[ti][0][kt] : Bs[0][kt], az);
        ar = mfma16(a[kt], (ti < 3) ? Bv[ti][1][kt] : Bs[1][kt], ar);
        ah = mfma16(a[kt], (ti < 3) ? Bv[ti][2][kt] : Bs[2][kt], ah);
      }
      float xzf[4] = {bflo(xzv[ti].x), bfhi(xzv[ti].x), bflo(xzv[ti].y), bfhi(xzv[ti].y)};
      float xrf[4] = {bflo(xrv[ti].x), bfhi(xrv[ti].x), bflo(xrv[ti].y), bfhi(xrv[ti].y)};
      float xhf[4] = {bflo(xhv[ti].x), bfhi(xhv[ti].x), bflo(xhv[ti].y), bfhi(xhv[ti].y)};
#pragma unroll
      for (int j = 0; j < 4; ++j) {
        float z = sigm(xzf[j] + az[j] + bz[ti]);
        float r = sigm(xrf[j] + ar[j] + br[ti]);
        float hc = sigm(xhf[j] + r * (ah[j] + bh[ti]));
        h1f[ti][j] = z * h1f[ti][j] + (1.0f - z) * hc;
      }
    }
    __syncthreads();
#pragma unroll
    for (int ti = 0; ti < 4; ++ti) {
      int tau = (ti < 3) ? (w * 3 + ti) : (12 + w);
#pragma unroll
      for (int j = 0; j < 4; ++j) {
        unsigned short hb = f2bf(h1f[ti][j]);
        h1b[(lr * 4 + j) * 264 + tau * 16 + lc] = hb;
        seq1[(((size_t)t * 8 + bblk) * 16 + (lr * 4 + j)) * 256 + tau * 16 + lc] = hb;
      }
    }
    __syncthreads();
  }
}

// ---------------------------------------------------------------------------
// xg2 = seq1 @ W2 + b2[0]  (tuple layout, H2=128 -> 8 taus, g in 0..2)
// ---------------------------------------------------------------------------
__global__ void __launch_bounds__(256) kxg2(const unsigned short* __restrict__ seq1,
                                            const unsigned short* __restrict__ W2p,
                                            const float* __restrict__ b2,
                                            unsigned short* __restrict__ xg2) {
  const int bblk = blockIdx.x, tch = blockIdx.y;
  const int tid = threadIdx.x;
  const int w = tid >> 6, l = tid & 63, lr = l >> 4, lc = l & 15;
  for (int ttg = 0; ttg < 4; ++ttg) {
    bf16x8 a[4][8];
#pragma unroll
    for (int m4 = 0; m4 < 4; ++m4) {
      int tglob = tch * 16 + ttg * 4 + m4;
#pragma unroll
      for (int kt = 0; kt < 8; ++kt)
        a[m4][kt] = ldfrag(seq1 + (((size_t)tglob * 8 + bblk) * 16 + lc) * 256 + kt * 32 + lr * 8);
    }
    for (int ni = 0; ni < 6; ++ni) {
      int nt = w * 6 + ni;  // 0..23
      bf16x8 bb[8];
#pragma unroll
      for (int kt = 0; kt < 8; ++kt)
        bb[kt] = ldfrag(W2p + (size_t)(nt * 8 + kt) * 512 + l * 8);
      float bias = b2[nt * 16 + lc];
      int g = nt >> 3, tau = nt & 7;
#pragma unroll
      for (int m4 = 0; m4 < 4; ++m4) {
        f32x4 acc = {0.f, 0.f, 0.f, 0.f};
#pragma unroll
        for (int kt = 0; kt < 8; ++kt) acc = mfma16(a[m4][kt], bb[kt], acc);
        int tglob = tch * 16 + ttg * 4 + m4;
        unsigned int u0 = (unsigned int)f2bf(acc[0] + bias) | ((unsigned int)f2bf(acc[1] + bias) << 16);
        unsigned int u1 = (unsigned int)f2bf(acc[2] + bias) | ((unsigned int)f2bf(acc[3] + bias) << 16);
        uint2 st; st.x = u0; st.y = u1;
        size_t base = ((((size_t)bblk * 512 + tglob) * 8 + tau) * 64 + l) * 12 + g * 4;
        *reinterpret_cast<uint2*>(xg2 + base) = st;
      }
    }
  }
}

// ---------------------------------------------------------------------------
// Layer-2 recurrence (H2=128, K=128, all U2 VGPR-resident: 2 triples/wave)
// ---------------------------------------------------------------------------
__global__ void __launch_bounds__(256) kscan2(const unsigned short* __restrict__ xg2,
                                              const unsigned short* __restrict__ U2p,
                                              const float* __restrict__ b2,
                                              unsigned short* __restrict__ seq2) {
  __shared__ __attribute__((aligned(16))) unsigned short h2b[16 * 136];
  const int bblk = blockIdx.x;
  const int tid = threadIdx.x;
  const int w = tid >> 6, l = tid & 63, lr = l >> 4, lc = l & 15;
  for (int i = tid; i < 16 * 136; i += 256) h2b[i] = 0;

  bf16x8 Bv[2][3][4];
#pragma unroll
  for (int ti = 0; ti < 2; ++ti)
#pragma unroll
    for (int g = 0; g < 3; ++g)
#pragma unroll
      for (int kt = 0; kt < 4; ++kt)
        Bv[ti][g][kt] = ldfrag(U2p + (size_t)((g * 8 + (2 * w + ti)) * 4 + kt) * 512 + l * 8);

  float bz[2], br[2], bh[2];
#pragma unroll
  for (int ti = 0; ti < 2; ++ti) {
    int n = (2 * w + ti) * 16 + lc;
    bz[ti] = b2[384 + n];
    br[ti] = b2[384 + 128 + n];
    bh[ti] = b2[384 + 256 + n];
  }

  const f32x4 zero4 = {0.f, 0.f, 0.f, 0.f};
  f32x4 h2f[2] = {zero4, zero4};

  __syncthreads();

  for (int t = 0; t < 512; ++t) {
    uint2 xzv[2], xrv[2], xhv[2];
#pragma unroll
    for (int ti = 0; ti < 2; ++ti) {
      const unsigned short* p = xg2 + ((((size_t)bblk * 512 + t) * 8 + (2 * w + ti)) * 64 + l) * 12;
      xzv[ti] = *reinterpret_cast<const uint2*>(p);
      xrv[ti] = *reinterpret_cast<const uint2*>(p + 4);
      xhv[ti] = *reinterpret_cast<const uint2*>(p + 8);
    }
    bf16x8 a[4];
#pragma unroll
    for (int kt = 0; kt < 4; ++kt)
      a[kt] = ldfrag(&h2b[lc * 136 + kt * 32 + lr * 8]);

#pragma unroll
    for (int ti = 0; ti < 2; ++ti) {
      f32x4 az = zero4, ar = zero4, ah = zero4;
#pragma unroll
      for (int kt = 0; kt < 4; ++kt) {
        az = mfma16(a[kt], Bv[ti][0][kt], az);
        ar = mfma16(a[kt], Bv[ti][1][kt], ar);
        ah = mfma16(a[kt], Bv[ti][2][kt], ah);
      }
      float xzf[4] = {bflo(xzv[ti].x), bfhi(xzv[ti].x), bflo(xzv[ti].y), bfhi(xzv[ti].y)};
      float xrf[4] = {bflo(xrv[ti].x), bfhi(xrv[ti].x), bflo(xrv[ti].y), bfhi(xrv[ti].y)};
      float xhf[4] = {bflo(xhv[ti].x), bfhi(xhv[ti].x), bflo(xhv[ti].y), bfhi(xhv[ti].y)};
#pragma unroll
      for (int j = 0; j < 4; ++j) {
        float z = sigm(xzf[j] + az[j] + bz[ti]);
        float r = sigm(xrf[j] + ar[j] + br[ti]);
        float hc = sigm(xhf[j] + r * (ah[j] + bh[ti]));
        h2f[ti][j] = z * h2f[ti][j] + (1.0f - z) * hc;
      }
    }
    __syncthreads();
#pragma unroll
    for (int ti = 0; ti < 2; ++ti) {
      int tau = 2 * w + ti;
#pragma unroll
      for (int j = 0; j < 4; ++j) {
        unsigned short hb = f2bf(h2f[ti][j]);
        h2b[(lr * 4 + j) * 136 + tau * 16 + lc] = hb;
        seq2[(((size_t)t * 8 + bblk) * 16 + (lr * 4 + j)) * 128 + tau * 16 + lc] = hb;
      }
    }
    __syncthreads();
  }
}

// ---------------------------------------------------------------------------
// xg3 = seq2 @ W3 + b3[0]  (tuple layout, H3=64 -> 4 taus)
// ---------------------------------------------------------------------------
__global__ void __launch_bounds__(256) kxg3(const unsigned short* __restrict__ seq2,
                                            const unsigned short* __restrict__ W3p,
                                            const float* __restrict__ b3,
                                            unsigned short* __restrict__ xg3) {
  const int bblk = blockIdx.x, tch = blockIdx.y;
  const int tid = threadIdx.x;
  const int w = tid >> 6, l = tid & 63, lr = l >> 4, lc = l & 15;
  for (int ttg = 0; ttg < 4; ++ttg) {
    bf16x8 a[4][4];
#pragma unroll
    for (int m4 = 0; m4 < 4; ++m4) {
      int tglob = tch * 16 + ttg * 4 + m4;
#pragma unroll
      for (int kt = 0; kt < 4; ++kt)
        a[m4][kt] = ldfrag(seq2 + (((size_t)tglob * 8 + bblk) * 16 + lc) * 128 + kt * 32 + lr * 8);
    }
    for (int ni = 0; ni < 3; ++ni) {
      int nt = w * 3 + ni;  // 0..11
      bf16x8 bb[4];
#pragma unroll
      for (int kt = 0; kt < 4; ++kt)
        bb[kt] = ldfrag(W3p + (size_t)(nt * 4 + kt) * 512 + l * 8);
      float bias = b3[nt * 16 + lc];
      int g = nt >> 2, tau = nt & 3;
#pragma unroll
      for (int m4 = 0; m4 < 4; ++m4) {
        f32x4 acc = {0.f, 0.f, 0.f, 0.f};
#pragma unroll
        for (int kt = 0; kt < 4; ++kt) acc = mfma16(a[m4][kt], bb[kt], acc);
        int tglob = tch * 16 + ttg * 4 + m4;
        unsigned int u0 = (unsigned int)f2bf(acc[0] + bias) | ((unsigned int)f2bf(acc[1] + bias) << 16);
        unsigned int u1 = (unsigned int)f2bf(acc[2] + bias) | ((unsigned int)f2bf(acc[3] + bias) << 16);
        uint2 st; st.x = u0; st.y = u1;
        size_t base = ((((size_t)bblk * 512 + tglob) * 4 + tau) * 64 + l) * 12 + g * 4;
        *reinterpret_cast<uint2*>(xg3 + base) = st;
      }
    }
  }
}

// ---------------------------------------------------------------------------
// Layer-3 recurrence (H3=64, K=64, relu candidate) + dense sigmoid head.
// ---------------------------------------------------------------------------
__global__ void __launch_bounds__(256) kscan3(const unsigned short* __restrict__ xg3,
                                              const unsigned short* __restrict__ U3p,
                                              const float* __restrict__ b3,
                                              const float* __restrict__ Wo,
                                              const float* __restrict__ bo,
                                              float* __restrict__ out) {
  __shared__ __attribute__((aligned(16))) unsigned short h3b[16 * 72];
  __shared__ float h3s[16 * 68];
  const int bblk = blockIdx.x;
  const int tid = threadIdx.x;
  const int w = tid >> 6, l = tid & 63, lr = l >> 4, lc = l & 15;
  for (int i = tid; i < 16 * 72; i += 256) h3b[i] = 0;

  bf16x8 Bv[3][2];
#pragma unroll
  for (int g = 0; g < 3; ++g)
#pragma unroll
    for (int kt = 0; kt < 2; ++kt)
      Bv[g][kt] = ldfrag(U3p + (size_t)((g * 4 + w) * 2 + kt) * 512 + l * 8);

  const int n3 = w * 16 + lc;
  const float bz = b3[192 + n3];
  const float br = b3[192 + 64 + n3];
  const float bh = b3[192 + 128 + n3];

  const f32x4 zero4 = {0.f, 0.f, 0.f, 0.f};
  f32x4 h3f = zero4;

  __syncthreads();

  for (int t = 0; t < 512; ++t) {
    const unsigned short* p = xg3 + ((((size_t)bblk * 512 + t) * 4 + w) * 64 + l) * 12;
    uint2 xzv = *reinterpret_cast<const uint2*>(p);
    uint2 xrv = *reinterpret_cast<const uint2*>(p + 4);
    uint2 xhv = *reinterpret_cast<const uint2*>(p + 8);

    bf16x8 a[2];
#pragma unroll
    for (int kt = 0; kt < 2; ++kt)
      a[kt] = ldfrag(&h3b[lc * 72 + kt * 32 + lr * 8]);

    f32x4 az = zero4, ar = zero4, ah = zero4;
#pragma unroll
    for (int kt = 0; kt < 2; ++kt) {
      az = mfma16(a[kt], Bv[0][kt], az);
      ar = mfma16(a[kt], Bv[1][kt], ar);
      ah = mfma16(a[kt], Bv[2][kt], ah);
    }
    float xzf[4] = {bflo(xzv.x), bfhi(xzv.x), bflo(xzv.y), bfhi(xzv.y)};
    float xrf[4] = {bflo(xrv.x), bfhi(xrv.x), bflo(xrv.y), bfhi(xrv.y)};
    float xhf[4] = {bflo(xhv.x), bfhi(xhv.x), bflo(xhv.y), bfhi(xhv.y)};
#pragma unroll
    for (int j = 0; j < 4; ++j) {
      float z = sigm(xzf[j] + az[j] + bz);
      float r = sigm(xrf[j] + ar[j] + br);
      float hc = fmaxf(0.0f, xhf[j] + r * (ah[j] + bh));  // relu candidate
      h3f[j] = z * h3f[j] + (1.0f - z) * hc;
    }
    __syncthreads();
#pragma unroll
    for (int j = 0; j < 4; ++j)
      h3b[(lr * 4 + j) * 72 + w * 16 + lc] = f2bf(h3f[j]);
    __syncthreads();
  }

  // dense head: out[b] = sigmoid(h3[b,:] . Wo + bo)
#pragma unroll
  for (int j = 0; j < 4; ++j)
    h3s[(lr * 4 + j) * 68 + w * 16 + lc] = h3f[j];
  __syncthreads();
  if (tid < 16) {
    float s = bo[0];
    for (int n = 0; n < 64; ++n) s += h3s[tid * 68 + n] * Wo[n];
    out[bblk * 16 + tid] = sigm(s);
  }
}

// ---------------------------------------------------------------------------
extern "C" void kernel_launch(void* const* d_in, const int* in_sizes, int n_in,
                              void* d_out, int out_size, void* d_ws, size_t ws_size,
                              hipStream_t stream) {
  (void)in_sizes; (void)n_in; (void)out_size; (void)ws_size;
  const float* text = (const float*)d_in[0];
  const float* W1 = (const float*)d_in[1];
  const float* U1 = (const float*)d_in[2];
  const float* b1 = (const float*)d_in[3];
  const float* W2 = (const float*)d_in[4];
  const float* U2 = (const float*)d_in[5];
  const float* b2 = (const float*)d_in[6];
  const float* W3 = (const float*)d_in[7];
  const float* U3 = (const float*)d_in[8];
  const float* b3 = (const float*)d_in[9];
  const float* Wo = (const float*)d_in[10];
  const float* bo = (const float*)d_in[11];
  float* out = (float*)d_out;
  char* ws = (char*)d_ws;

  // workspace layout (ushort elements)
  unsigned short* W1p = (unsigned short*)ws;          // 98304
  unsigned short* U1p = W1p + 98304;                  // 196608
  unsigned short* W2p = U1p + 196608;                 // 98304
  unsigned short* U2p = W2p + 98304;                  // 49152
  unsigned short* W3p = U2p + 49152;                  // 24576
  unsigned short* U3p = W3p + 24576;                  // 12288
  unsigned short* big = (unsigned short*)(ws + 1048576);  // xg1 (50331648) / xg2 (25165824)
  unsigned short* seq1 = big + 50331648;              // 16777216 / later xg3 (12582912)
  unsigned short* seq2 = seq1 + 16777216;             // 8388608
  unsigned short* xg1 = big;
  unsigned short* xg2 = big;
  unsigned short* xg3 = seq1;

  // weight permutes (fragment layout, bf16)
  kperm<<<192, 64, 0, stream>>>(W1, W1p, 128, 768);
  kperm<<<384, 64, 0, stream>>>(U1, U1p, 256, 768);
  kperm<<<192, 64, 0, stream>>>(W2, W2p, 256, 384);
  kperm<<<96, 64, 0, stream>>>(U2, U2p, 128, 384);
  kperm<<<48, 64, 0, stream>>>(W3, W3p, 128, 192);
  kperm<<<24, 64, 0, stream>>>(U3, U3p, 64, 192);

  kxg1<<<dim3(8, 32), 256, 0, stream>>>(text, W1p, b1, xg1);
  kscan1<<<8, 256, 0, stream>>>(xg1, U1p, b1, seq1);
  kxg2<<<dim3(8, 32), 256, 0, stream>>>(seq1, W2p, b2, xg2);
  kscan2<<<8, 256, 0, stream>>>(xg2, U2p, b2, seq2);
  kxg3<<<dim3(8, 32), 256, 0, stream>>>(seq2, W3p, b3, xg3);
  kscan3<<<8, 256, 0, stream>>>(xg3, U3p, b3, Wo, bo, out);
}

// Round 2
// 2045.287 us; speedup vs baseline: 1.6569x; 1.6569x over previous
//
#include <hip/hip_runtime.h>

// ---------------------------------------------------------------------------
// GRU stack: 3 layers (H=256,128,64) over [B=128,T=512,F=128] + dense sigmoid.
// R1: 8-wave scans (U fully reg-resident via unified VGPR/AGPR), coalesced
// per-(t,tau,gate) xg layout with 1-step register prefetch, log2e-prescaled
// fast sigmoid (exp2+rcp), z/r recurrent biases folded into xg GEMMs.
// ---------------------------------------------------------------------------

typedef __attribute__((ext_vector_type(8))) __bf16 bf16x8;
typedef __attribute__((ext_vector_type(4))) float f32x4;

#define DEVINL __device__ __forceinline__
#define LOG2E 1.44269504088896340736f

DEVINL unsigned short bfbits(float f) {  // f32 -> bf16 bits (RNE via HW cvt)
  __bf16 h = (__bf16)f;
  unsigned short u;
  __builtin_memcpy(&u, &h, 2);
  return u;
}
DEVINL unsigned int pkbf(float a, float b) {
  return (unsigned int)bfbits(a) | ((unsigned int)bfbits(b) << 16);
}
DEVINL float bflo(unsigned int u) { return __uint_as_float(u << 16); }
DEVINL float bfhi(unsigned int u) { return __uint_as_float(u & 0xffff0000u); }

DEVINL float sigm(float x) {  // plain sigmoid (head only)
  return __builtin_amdgcn_rcpf(1.0f + __expf(-x));
}
DEVINL float sigm2(float y) {  // sigmoid(x) where y = x * log2(e)
#if __has_builtin(__builtin_amdgcn_exp2f)
  float e = __builtin_amdgcn_exp2f(-y);
#else
  float e = exp2f(-y);
#endif
  return __builtin_amdgcn_rcpf(1.0f + e);
}

DEVINL f32x4 mfma16(bf16x8 a, bf16x8 b, f32x4 c) {
  return __builtin_amdgcn_mfma_f32_16x16x32_bf16(a, b, c, 0, 0, 0);
}
DEVINL bf16x8 ldfrag(const unsigned short* p) {
  return *reinterpret_cast<const bf16x8*>(p);
}

// ---------------------------------------------------------------------------
// Weight permute: src fp32 [K,N] -> dst bf16 B-fragments, cols < n_scaled
// prescaled by log2(e) (sigmoid-path gates). Fragment (ntile,ktile): lane l
// elem j = src[ktile*32 + (l>>4)*8 + j][ntile*16 + (l&15)].
// ---------------------------------------------------------------------------
__global__ void kperm(const float* __restrict__ src, unsigned short* __restrict__ dst,
                      int K, int N, int n_scaled) {
  int KT = K >> 5;
  int tile = blockIdx.x;
  int ntile = tile / KT, ktile = tile - ntile * KT;
  int l = threadIdx.x;
  int col = ntile * 16 + (l & 15);
  int krow = ktile * 32 + ((l >> 4) << 3);
  float sc = (col < n_scaled) ? LOG2E : 1.0f;
  unsigned short tmp[8];
#pragma unroll
  for (int j = 0; j < 8; ++j) tmp[j] = bfbits(src[(size_t)(krow + j) * N + col] * sc);
  uint4 v;
  v.x = (unsigned int)tmp[0] | ((unsigned int)tmp[1] << 16);
  v.y = (unsigned int)tmp[2] | ((unsigned int)tmp[3] << 16);
  v.z = (unsigned int)tmp[4] | ((unsigned int)tmp[5] << 16);
  v.w = (unsigned int)tmp[6] | ((unsigned int)tmp[7] << 16);
  *reinterpret_cast<uint4*>(dst + (size_t)(tile * 64 + l) * 8) = v;
}

// ---------------------------------------------------------------------------
// xg layouts (ushort): idx = ((((bblk*512+t)*NTAU + tau)*3 + g)*64 + l)*4 + j
// -> per (t,tau,g) a contiguous 512B chunk, lane offset l*8 (coalesced).
// Gate value (lane l, j) is batch row lr*4+j, hidden col tau*16+lc.
// z/r chunks include input+recurrent bias; h chunk input bias only.
// Layers 1-2: all gates prescaled by log2e; layer 3: only z/r.
// ---------------------------------------------------------------------------
__global__ void __launch_bounds__(256) kxg1(const float* __restrict__ text,
                                            const unsigned short* __restrict__ W1p,
                                            const float* __restrict__ b1,
                                            unsigned short* __restrict__ xg1) {
  __shared__ __attribute__((aligned(16))) unsigned short alds[16 * 2184];  // [b][tt][136pad]
  const int bblk = blockIdx.x, tch = blockIdx.y;
  const int tid = threadIdx.x;
  {
    int tt = tid >> 4, kc = tid & 15;
#pragma unroll
    for (int b = 0; b < 16; ++b) {
      const float* p = text + ((size_t)((bblk * 16 + b) * 512 + tch * 16 + tt)) * 128 + kc * 8;
      float4 f0 = *reinterpret_cast<const float4*>(p);
      float4 f1 = *reinterpret_cast<const float4*>(p + 4);
      uint4 v;
      v.x = pkbf(f0.x, f0.y);
      v.y = pkbf(f0.z, f0.w);
      v.z = pkbf(f1.x, f1.y);
      v.w = pkbf(f1.z, f1.w);
      *reinterpret_cast<uint4*>(&alds[b * 2184 + tt * 136 + kc * 8]) = v;
    }
  }
  __syncthreads();
  const int w = tid >> 6, l = tid & 63, lr = l >> 4, lc = l & 15;
  for (int mtg = 0; mtg < 4; ++mtg) {
    bf16x8 a[4][4];
#pragma unroll
    for (int m4 = 0; m4 < 4; ++m4)
#pragma unroll
      for (int kt = 0; kt < 4; ++kt)
        a[m4][kt] = ldfrag(&alds[lc * 2184 + (mtg * 4 + m4) * 136 + kt * 32 + lr * 8]);
    for (int ni = 0; ni < 12; ++ni) {
      int nt = w * 12 + ni;  // 0..47
      bf16x8 bb[4];
#pragma unroll
      for (int kt = 0; kt < 4; ++kt)
        bb[kt] = ldfrag(W1p + (size_t)(nt * 4 + kt) * 512 + l * 8);
      int g = nt >> 4, tau = nt & 15;
      int n = nt * 16 + lc;
      float bias = (b1[n] + ((g < 2) ? b1[768 + n] : 0.f)) * LOG2E;
#pragma unroll
      for (int m4 = 0; m4 < 4; ++m4) {
        f32x4 acc = {0.f, 0.f, 0.f, 0.f};
#pragma unroll
        for (int kt = 0; kt < 4; ++kt) acc = mfma16(a[m4][kt], bb[kt], acc);
        int tglob = tch * 16 + mtg * 4 + m4;
        uint2 st;
        st.x = pkbf(acc[0] + bias, acc[1] + bias);
        st.y = pkbf(acc[2] + bias, acc[3] + bias);
        size_t base = ((((size_t)bblk * 512 + tglob) * 16 + tau) * 3 + g) * 256 + (size_t)l * 4;
        *reinterpret_cast<uint2*>(xg1 + base) = st;
      }
    }
  }
}

// ---------------------------------------------------------------------------
// Layer-1 recurrence: 8 blocks x 512 threads (8 waves, 2/SIMD).
// Wave w owns taus {2w, 2w+1}; all U1 fragments register-resident
// (unified VGPR+AGPR file). xg prefetched one step ahead (ping-pong).
// ---------------------------------------------------------------------------
__global__ void __launch_bounds__(512, 2) kscan1(const unsigned short* __restrict__ xg1,
                                                 const unsigned short* __restrict__ U1p,
                                                 const float* __restrict__ b1,
                                                 unsigned short* __restrict__ seq1) {
  __shared__ __attribute__((aligned(16))) unsigned short h1b[16 * 264];
  const int bblk = blockIdx.x;
  const int tid = threadIdx.x;
  const int w = tid >> 6, l = tid & 63, lr = l >> 4, lc = l & 15;
  const int tau0 = 2 * w;

  for (int i = tid; i < 16 * 264; i += 512) h1b[i] = 0;

  bf16x8 Bv[2][3][8];
#pragma unroll
  for (int ti = 0; ti < 2; ++ti)
#pragma unroll
    for (int g = 0; g < 3; ++g)
#pragma unroll
      for (int kt = 0; kt < 8; ++kt)
        Bv[ti][g][kt] = ldfrag(U1p + (size_t)((g * 16 + (tau0 + ti)) * 8 + kt) * 512 + l * 8);

  const float bh0 = b1[768 + 512 + tau0 * 16 + lc] * LOG2E;
  const float bh1 = b1[768 + 512 + (tau0 + 1) * 16 + lc] * LOG2E;

  const unsigned short* p0 = xg1 + (size_t)bblk * 512 * 12288 + (size_t)tau0 * 768 + l * 4;
  const unsigned short* p1 = p0 + 768;
  unsigned short* sq = seq1 + ((size_t)bblk * 16 + lr * 4) * 256 + lc;

  const f32x4 z4 = {0.f, 0.f, 0.f, 0.f};
  f32x4 h0 = z4, h1 = z4;

  uint2 AZ0, AR0, AH0, AZ1, AR1, AH1, BZ0, BR0, BH0, BZ1, BR1, BH1;

#define LDX1(Z0, R0, H0v, Z1, R1, H1v)                          \
  {                                                             \
    Z0 = *reinterpret_cast<const uint2*>(p0);                   \
    R0 = *reinterpret_cast<const uint2*>(p0 + 256);             \
    H0v = *reinterpret_cast<const uint2*>(p0 + 512);            \
    Z1 = *reinterpret_cast<const uint2*>(p1);                   \
    R1 = *reinterpret_cast<const uint2*>(p1 + 256);             \
    H1v = *reinterpret_cast<const uint2*>(p1 + 512);            \
    p0 += 12288;                                                \
    p1 += 12288;                                                \
  }

#define GATES1(TI, XZ, XR, XH, HF, BH)                                          \
  {                                                                             \
    f32x4 az = z4, ar = z4, ah = z4;                                            \
    _Pragma("unroll") for (int kt = 0; kt < 8; ++kt) {                          \
      az = mfma16(a[kt], Bv[TI][0][kt], az);                                    \
      ar = mfma16(a[kt], Bv[TI][1][kt], ar);                                    \
      ah = mfma16(a[kt], Bv[TI][2][kt], ah);                                    \
    }                                                                           \
    float xzf[4] = {bflo(XZ.x), bfhi(XZ.x), bflo(XZ.y), bfhi(XZ.y)};            \
    float xrf[4] = {bflo(XR.x), bfhi(XR.x), bflo(XR.y), bfhi(XR.y)};            \
    float xhf[4] = {bflo(XH.x), bfhi(XH.x), bflo(XH.y), bfhi(XH.y)};            \
    _Pragma("unroll") for (int j = 0; j < 4; ++j) {                             \
      float zz = sigm2(xzf[j] + az[j]);                                         \
      float rr = sigm2(xrf[j] + ar[j]);                                         \
      float hc = sigm2(__builtin_fmaf(rr, ah[j] + (BH), xhf[j]));               \
      HF[j] = hc + zz * (HF[j] - hc);                                           \
    }                                                                           \
  }

#define STORE1(TAU, HF)                                                \
  {                                                                    \
    _Pragma("unroll") for (int j = 0; j < 4; ++j) {                    \
      unsigned short hb = bfbits(HF[j]);                               \
      h1b[(lr * 4 + j) * 264 + (TAU) * 16 + lc] = hb;                  \
      sq[(size_t)j * 256 + (TAU) * 16] = hb;                           \
    }                                                                  \
  }

#define STEP1(CZ0, CR0, CH0, CZ1, CR1, CH1, NZ0, NR0, NH0, NZ1, NR1, NH1) \
  {                                                                       \
    LDX1(NZ0, NR0, NH0, NZ1, NR1, NH1);                                   \
    __syncthreads();                                                      \
    bf16x8 a[8];                                                          \
    _Pragma("unroll") for (int kt = 0; kt < 8; ++kt)                      \
        a[kt] = ldfrag(&h1b[lc * 264 + kt * 32 + lr * 8]);                \
    GATES1(0, CZ0, CR0, CH0, h0, bh0);                                    \
    GATES1(1, CZ1, CR1, CH1, h1, bh1);                                    \
    __syncthreads();                                                      \
    STORE1(tau0, h0);                                                     \
    STORE1(tau0 + 1, h1);                                                 \
    sq += 32768;                                                          \
  }

  LDX1(AZ0, AR0, AH0, AZ1, AR1, AH1);
  for (int t = 0; t < 512; t += 2) {
    STEP1(AZ0, AR0, AH0, AZ1, AR1, AH1, BZ0, BR0, BH0, BZ1, BR1, BH1);
    STEP1(BZ0, BR0, BH0, BZ1, BR1, BH1, AZ0, AR0, AH0, AZ1, AR1, AH1);
  }
#undef LDX1
#undef GATES1
#undef STORE1
#undef STEP1
}

// ---------------------------------------------------------------------------
// xg2 = seq1 @ W2 (+ folded biases), coalesced tuple layout (NTAU=8)
// ---------------------------------------------------------------------------
__global__ void __launch_bounds__(256) kxg2(const unsigned short* __restrict__ seq1,
                                            const unsigned short* __restrict__ W2p,
                                            const float* __restrict__ b2,
                                            unsigned short* __restrict__ xg2) {
  const int bblk = blockIdx.x, tch = blockIdx.y;
  const int tid = threadIdx.x;
  const int w = tid >> 6, l = tid & 63, lr = l >> 4, lc = l & 15;
  for (int ttg = 0; ttg < 4; ++ttg) {
    bf16x8 a[4][8];
#pragma unroll
    for (int m4 = 0; m4 < 4; ++m4) {
      int tglob = tch * 16 + ttg * 4 + m4;
#pragma unroll
      for (int kt = 0; kt < 8; ++kt)
        a[m4][kt] = ldfrag(seq1 + (((size_t)tglob * 8 + bblk) * 16 + lc) * 256 + kt * 32 + lr * 8);
    }
    for (int ni = 0; ni < 6; ++ni) {
      int nt = w * 6 + ni;  // 0..23
      bf16x8 bb[8];
#pragma unroll
      for (int kt = 0; kt < 8; ++kt)
        bb[kt] = ldfrag(W2p + (size_t)(nt * 8 + kt) * 512 + l * 8);
      int g = nt >> 3, tau = nt & 7;
      int n = nt * 16 + lc;
      float bias = (b2[n] + ((g < 2) ? b2[384 + n] : 0.f)) * LOG2E;
#pragma unroll
      for (int m4 = 0; m4 < 4; ++m4) {
        f32x4 acc = {0.f, 0.f, 0.f, 0.f};
#pragma unroll
        for (int kt = 0; kt < 8; ++kt) acc = mfma16(a[m4][kt], bb[kt], acc);
        int tglob = tch * 16 + ttg * 4 + m4;
        uint2 st;
        st.x = pkbf(acc[0] + bias, acc[1] + bias);
        st.y = pkbf(acc[2] + bias, acc[3] + bias);
        size_t base = ((((size_t)bblk * 512 + tglob) * 8 + tau) * 3 + g) * 256 + (size_t)l * 4;
        *reinterpret_cast<uint2*>(xg2 + base) = st;
      }
    }
  }
}

// ---------------------------------------------------------------------------
// Layer-2 recurrence: 8 blocks x 512 threads, wave w owns tau=w (H2=128).
// ---------------------------------------------------------------------------
__global__ void __launch_bounds__(512, 2) kscan2(const unsigned short* __restrict__ xg2,
                                                 const unsigned short* __restrict__ U2p,
                                                 const float* __restrict__ b2,
                                                 unsigned short* __restrict__ seq2) {
  __shared__ __attribute__((aligned(16))) unsigned short h2b[16 * 136];
  const int bblk = blockIdx.x;
  const int tid = threadIdx.x;
  const int w = tid >> 6, l = tid & 63, lr = l >> 4, lc = l & 15;
  for (int i = tid; i < 16 * 136; i += 512) h2b[i] = 0;

  bf16x8 Bv[3][4];
#pragma unroll
  for (int g = 0; g < 3; ++g)
#pragma unroll
    for (int kt = 0; kt < 4; ++kt)
      Bv[g][kt] = ldfrag(U2p + (size_t)((g * 8 + w) * 4 + kt) * 512 + l * 8);

  const float bh = b2[384 + 256 + w * 16 + lc] * LOG2E;

  const unsigned short* p = xg2 + (size_t)bblk * 512 * 6144 + (size_t)w * 768 + l * 4;
  unsigned short* sq = seq2 + ((size_t)bblk * 16 + lr * 4) * 128 + lc;

  const f32x4 z4 = {0.f, 0.f, 0.f, 0.f};
  f32x4 hf = z4;
  uint2 AZ, AR, AH, BZ, BR, BH2;

#define LDX2(Z, R, Hv)                                  \
  {                                                     \
    Z = *reinterpret_cast<const uint2*>(p);             \
    R = *reinterpret_cast<const uint2*>(p + 256);       \
    Hv = *reinterpret_cast<const uint2*>(p + 512);      \
    p += 6144;                                          \
  }

#define STEP2(CZ, CR, CH, NZ, NR, NH)                                           \
  {                                                                             \
    LDX2(NZ, NR, NH);                                                           \
    __syncthreads();                                                            \
    bf16x8 a[4];                                                                \
    _Pragma("unroll") for (int kt = 0; kt < 4; ++kt)                            \
        a[kt] = ldfrag(&h2b[lc * 136 + kt * 32 + lr * 8]);                      \
    f32x4 az = z4, ar = z4, ah = z4;                                            \
    _Pragma("unroll") for (int kt = 0; kt < 4; ++kt) {                          \
      az = mfma16(a[kt], Bv[0][kt], az);                                        \
      ar = mfma16(a[kt], Bv[1][kt], ar);                                        \
      ah = mfma16(a[kt], Bv[2][kt], ah);                                        \
    }                                                                           \
    float xzf[4] = {bflo(CZ.x), bfhi(CZ.x), bflo(CZ.y), bfhi(CZ.y)};            \
    float xrf[4] = {bflo(CR.x), bfhi(CR.x), bflo(CR.y), bfhi(CR.y)};            \
    float xhf[4] = {bflo(CH.x), bfhi(CH.x), bflo(CH.y), bfhi(CH.y)};            \
    _Pragma("unroll") for (int j = 0; j < 4; ++j) {                             \
      float zz = sigm2(xzf[j] + az[j]);                                         \
      float rr = sigm2(xrf[j] + ar[j]);                                         \
      float hc = sigm2(__builtin_fmaf(rr, ah[j] + bh, xhf[j]));                 \
      hf[j] = hc + zz * (hf[j] - hc);                                           \
    }                                                                           \
    __syncthreads();                                                            \
    _Pragma("unroll") for (int j = 0; j < 4; ++j) {                             \
      unsigned short hb = bfbits(hf[j]);                                        \
      h2b[(lr * 4 + j) * 136 + w * 16 + lc] = hb;                               \
      sq[(size_t)j * 128 + w * 16] = hb;                                        \
    }                                                                           \
    sq += 16384;                                                                \
  }

  LDX2(AZ, AR, AH);
  for (int t = 0; t < 512; t += 2) {
    STEP2(AZ, AR, AH, BZ, BR, BH2);
    STEP2(BZ, BR, BH2, AZ, AR, AH);
  }
#undef LDX2
#undef STEP2
}

// ---------------------------------------------------------------------------
// xg3 = seq2 @ W3 (+ folded z/r biases; h-gate unscaled), NTAU=4
// ---------------------------------------------------------------------------
__global__ void __launch_bounds__(256) kxg3(const unsigned short* __restrict__ seq2,
                                            const unsigned short* __restrict__ W3p,
                                            const float* __restrict__ b3,
                                            unsigned short* __restrict__ xg3) {
  const int bblk = blockIdx.x, tch = blockIdx.y;
  const int tid = threadIdx.x;
  const int w = tid >> 6, l = tid & 63, lr = l >> 4, lc = l & 15;
  for (int ttg = 0; ttg < 4; ++ttg) {
    bf16x8 a[4][4];
#pragma unroll
    for (int m4 = 0; m4 < 4; ++m4) {
      int tglob = tch * 16 + ttg * 4 + m4;
#pragma unroll
      for (int kt = 0; kt < 4; ++kt)
        a[m4][kt] = ldfrag(seq2 + (((size_t)tglob * 8 + bblk) * 16 + lc) * 128 + kt * 32 + lr * 8);
    }
    for (int ni = 0; ni < 3; ++ni) {
      int nt = w * 3 + ni;  // 0..11
      bf16x8 bb[4];
#pragma unroll
      for (int kt = 0; kt < 4; ++kt)
        bb[kt] = ldfrag(W3p + (size_t)(nt * 4 + kt) * 512 + l * 8);
      int g = nt >> 2, tau = nt & 3;
      int n = nt * 16 + lc;
      float bias = b3[n] + ((g < 2) ? b3[192 + n] : 0.f);
      if (g < 2) bias *= LOG2E;
#pragma unroll
      for (int m4 = 0; m4 < 4; ++m4) {
        f32x4 acc = {0.f, 0.f, 0.f, 0.f};
#pragma unroll
        for (int kt = 0; kt < 4; ++kt) acc = mfma16(a[m4][kt], bb[kt], acc);
        int tglob = tch * 16 + ttg * 4 + m4;
        uint2 st;
        st.x = pkbf(acc[0] + bias, acc[1] + bias);
        st.y = pkbf(acc[2] + bias, acc[3] + bias);
        size_t base = ((((size_t)bblk * 512 + tglob) * 4 + tau) * 3 + g) * 256 + (size_t)l * 4;
        *reinterpret_cast<uint2*>(xg3 + base) = st;
      }
    }
  }
}

// ---------------------------------------------------------------------------
// Layer-3 recurrence (H3=64, relu candidate, unscaled h-path) + dense head.
// 8 blocks x 256 threads (4 waves), tau = w.
// ---------------------------------------------------------------------------
__global__ void __launch_bounds__(256) kscan3(const unsigned short* __restrict__ xg3,
                                              const unsigned short* __restrict__ U3p,
                                              const float* __restrict__ b3,
                                              const float* __restrict__ Wo,
                                              const float* __restrict__ bo,
                                              float* __restrict__ out) {
  __shared__ __attribute__((aligned(16))) unsigned short h3b[16 * 72];
  __shared__ float h3s[16 * 68];
  const int bblk = blockIdx.x;
  const int tid = threadIdx.x;
  const int w = tid >> 6, l = tid & 63, lr = l >> 4, lc = l & 15;
  for (int i = tid; i < 16 * 72; i += 256) h3b[i] = 0;

  bf16x8 Bv[3][2];
#pragma unroll
  for (int g = 0; g < 3; ++g)
#pragma unroll
    for (int kt = 0; kt < 2; ++kt)
      Bv[g][kt] = ldfrag(U3p + (size_t)((g * 4 + w) * 2 + kt) * 512 + l * 8);

  const float bh = b3[192 + 128 + w * 16 + lc];  // raw (relu path)

  const unsigned short* p = xg3 + (size_t)bblk * 512 * 3072 + (size_t)w * 768 + l * 4;

  const f32x4 z4 = {0.f, 0.f, 0.f, 0.f};
  f32x4 hf = z4;
  uint2 AZ, AR, AH, BZ, BR, BH3;

#define LDX3(Z, R, Hv)                                  \
  {                                                     \
    Z = *reinterpret_cast<const uint2*>(p);             \
    R = *reinterpret_cast<const uint2*>(p + 256);       \
    Hv = *reinterpret_cast<const uint2*>(p + 512);      \
    p += 3072;                                          \
  }

#define STEP3(CZ, CR, CH, NZ, NR, NH)                                           \
  {                                                                             \
    LDX3(NZ, NR, NH);                                                           \
    __syncthreads();                                                            \
    bf16x8 a[2];                                                                \
    _Pragma("unroll") for (int kt = 0; kt < 2; ++kt)                            \
        a[kt] = ldfrag(&h3b[lc * 72 + kt * 32 + lr * 8]);                       \
    f32x4 az = z4, ar = z4, ah = z4;                                            \
    _Pragma("unroll") for (int kt = 0; kt < 2; ++kt) {                          \
      az = mfma16(a[kt], Bv[0][kt], az);                                        \
      ar = mfma16(a[kt], Bv[1][kt], ar);                                        \
      ah = mfma16(a[kt], Bv[2][kt], ah);                                        \
    }                                                                           \
    float xzf[4] = {bflo(CZ.x), bfhi(CZ.x), bflo(CZ.y), bfhi(CZ.y)};            \
    float xrf[4] = {bflo(CR.x), bfhi(CR.x), bflo(CR.y), bfhi(CR.y)};            \
    float xhf[4] = {bflo(CH.x), bfhi(CH.x), bflo(CH.y), bfhi(CH.y)};            \
    _Pragma("unroll") for (int j = 0; j < 4; ++j) {                             \
      float zz = sigm2(xzf[j] + az[j]);                                         \
      float rr = sigm2(xrf[j] + ar[j]);                                         \
      float hc = fmaxf(0.0f, __builtin_fmaf(rr, ah[j] + bh, xhf[j]));           \
      hf[j] = hc + zz * (hf[j] - hc);                                           \
    }                                                                           \
    __syncthreads();                                                            \
    _Pragma("unroll") for (int j = 0; j < 4; ++j)                               \
        h3b[(lr * 4 + j) * 72 + w * 16 + lc] = bfbits(hf[j]);                   \
  }

  LDX3(AZ, AR, AH);
  for (int t = 0; t < 512; t += 2) {
    STEP3(AZ, AR, AH, BZ, BR, BH3);
    STEP3(BZ, BR, BH3, AZ, AR, AH);
  }
#undef LDX3
#undef STEP3

  // dense head: out[b] = sigmoid(h3[b,:] . Wo + bo)
#pragma unroll
  for (int j = 0; j < 4; ++j)
    h3s[(lr * 4 + j) * 68 + w * 16 + lc] = hf[j];
  __syncthreads();
  if (tid < 16) {
    float s = bo[0];
    for (int n = 0; n < 64; ++n) s += h3s[tid * 68 + n] * Wo[n];
    out[bblk * 16 + tid] = sigm(s);
  }
}

// ---------------------------------------------------------------------------
extern "C" void kernel_launch(void* const* d_in, const int* in_sizes, int n_in,
                              void* d_out, int out_size, void* d_ws, size_t ws_size,
                              hipStream_t stream) {
  (void)in_sizes; (void)n_in; (void)out_size; (void)ws_size;
  const float* text = (const float*)d_in[0];
  const float* W1 = (const float*)d_in[1];
  const float* U1 = (const float*)d_in[2];
  const float* b1 = (const float*)d_in[3];
  const float* W2 = (const float*)d_in[4];
  const float* U2 = (const float*)d_in[5];
  const float* b2 = (const float*)d_in[6];
  const float* W3 = (const float*)d_in[7];
  const float* U3 = (const float*)d_in[8];
  const float* b3 = (const float*)d_in[9];
  const float* Wo = (const float*)d_in[10];
  const float* bo = (const float*)d_in[11];
  float* out = (float*)d_out;
  char* ws = (char*)d_ws;

  // workspace layout (ushort elements)
  unsigned short* W1p = (unsigned short*)ws;              // 98304
  unsigned short* U1p = W1p + 98304;                      // 196608
  unsigned short* W2p = U1p + 196608;                     // 98304
  unsigned short* U2p = W2p + 98304;                      // 49152
  unsigned short* W3p = U2p + 49152;                      // 24576
  unsigned short* U3p = W3p + 24576;                      // 12288
  unsigned short* big = (unsigned short*)(ws + 1048576);  // xg1 / xg2
  unsigned short* seq1 = big + 50331648;                  // 16777216 / xg3
  unsigned short* seq2 = seq1 + 16777216;                 // 8388608
  unsigned short* xg1 = big;
  unsigned short* xg2 = big;
  unsigned short* xg3 = seq1;

  // weight permutes (fragment layout, bf16, sigmoid-gate prescale by log2e)
  kperm<<<192, 64, 0, stream>>>(W1, W1p, 128, 768, 768);
  kperm<<<384, 64, 0, stream>>>(U1, U1p, 256, 768, 768);
  kperm<<<192, 64, 0, stream>>>(W2, W2p, 256, 384, 384);
  kperm<<<96, 64, 0, stream>>>(U2, U2p, 128, 384, 384);
  kperm<<<48, 64, 0, stream>>>(W3, W3p, 128, 192, 128);
  kperm<<<24, 64, 0, stream>>>(U3, U3p, 64, 192, 128);

  kxg1<<<dim3(8, 32), 256, 0, stream>>>(text, W1p, b1, xg1);
  kscan1<<<8, 512, 0, stream>>>(xg1, U1p, b1, seq1);
  kxg2<<<dim3(8, 32), 256, 0, stream>>>(seq1, W2p, b2, xg2);
  kscan2<<<8, 512, 0, stream>>>(xg2, U2p, b2, seq2);
  kxg3<<<dim3(8, 32), 256, 0, stream>>>(seq2, W3p, b3, xg3);
  kscan3<<<8, 256, 0, stream>>>(xg3, U3p, b3, Wo, bo, out);
}